// Round 16
// baseline (206.598 us; speedup 1.0000x reference)
//
#include <hip/hip_runtime.h>
#include <math.h>

#define NROWS 16384   // B*T
#define INCH  512
#define CH    2048
#define DD    256
#define MM    1024

typedef unsigned short u16;
typedef short short8 __attribute__((ext_vector_type(8)));
typedef float f32x4 __attribute__((ext_vector_type(4)));

__device__ __forceinline__ u16 f2bf(float f) {
  unsigned u = __float_as_uint(f);
  return (u16)((u + 0x7fffu + ((u >> 16) & 1u)) >> 16);
}
__device__ __forceinline__ float bf2f(u16 h) {
  return __uint_as_float(((unsigned)h) << 16);
}
__device__ __forceinline__ void gload16(const u16* g, u16* lds) {
  __builtin_amdgcn_global_load_lds((const __attribute__((address_space(1))) void*)g,
                                   (__attribute__((address_space(3))) void*)lds, 16, 0, 0);
}

// Coalesced-staging chunk mapping (16B chunks of 8 bf16 along K):
//   PC(row,kc) = (row>>4)*64 + (row&15)*4 + (kc ^ ((row>>1)&3))
//   frag read: chunk = group*64 + rI, rI = (lane&15)*4 + ((lane>>4)^((lane>>1)&3))

// ---------------------------------------------------------------------------
// K0: X fp32 -> bf16 (row-major, each element converted exactly once)
// ---------------------------------------------------------------------------
__global__ __launch_bounds__(256) void k_split_x(const float* __restrict__ x,
                                                 u16* __restrict__ xb) {
  const size_t i = ((size_t)blockIdx.x * 256 + threadIdx.x) * 8;
  float4 a = *(const float4*)(x + i);
  float4 b = *(const float4*)(x + i + 4);
  float v[8] = {a.x, a.y, a.z, a.w, b.x, b.y, b.z, b.w};
  unsigned hw[4];
#pragma unroll
  for (int p = 0; p < 4; ++p)
    hw[p] = (unsigned)f2bf(v[2 * p]) | ((unsigned)f2bf(v[2 * p + 1]) << 16);
  *(uint4*)(xb + i) = make_uint4(hw[0], hw[1], hw[2], hw[3]);
}

// src [R][C] fp32  ->  d [C][R] bf16 (transpose + round)
__global__ __launch_bounds__(256) void k_split_wT(const float* __restrict__ src,
                                                  u16* __restrict__ dh, int R, int C) {
  __shared__ float t[32][33];
  const int tx = threadIdx.x & 31, ty = threadIdx.x >> 5;
  const int c0 = blockIdx.x * 32, r0 = blockIdx.y * 32;
#pragma unroll
  for (int i = 0; i < 4; ++i)
    t[ty + i * 8][tx] = src[(size_t)(r0 + ty + i * 8) * C + c0 + tx];
  __syncthreads();
#pragma unroll
  for (int i = 0; i < 4; ++i) {
    float v = t[tx][ty + i * 8];
    dh[(size_t)(c0 + ty + i * 8) * R + r0 + tx] = f2bf(v);
  }
}

// ---------------------------------------------------------------------------
// K1: H = bf16(Xb @ W1).  128x128 tile, BK=32, 4 waves (2x2), 32KB dbuf LDS.
// Both operands via global_load_lds. XCD-swizzled grid (2048).
// ---------------------------------------------------------------------------
__global__ __launch_bounds__(256) void k_gemm1(const u16* __restrict__ Xb,
                                               const u16* __restrict__ W1ht,
                                               u16* __restrict__ Hh,
                                               float* __restrict__ STATS) {
  __shared__ u16 sm[2][1024 * 8];   // 32 KB
  const int tid = threadIdx.x;
  const int lane = tid & 63, w = tid >> 6;
  const int wr = w >> 1, wc = w & 1;
  const int hw = blockIdx.x;
  const int u = hw >> 3;
  const int by = (hw & 7) * 16 + (u >> 4);   // [0,128)
  const int bx = u & 15;                     // [0,16)
  const int gm = by * 128, n0 = bx * 128;

  f32x4 acc[4][4];
#pragma unroll
  for (int i = 0; i < 4; ++i)
#pragma unroll
    for (int j = 0; j < 4; ++j) acc[i][j] = (f32x4){0.f, 0.f, 0.f, 0.f};

  auto STAGE = [&](int buf, int kt) {
#pragma unroll
    for (int t = 0; t < 4; ++t) {
      const int f = t * 256 + tid;            // [0,1024)
      const int isB = f >> 9;                 // wave-uniform
      const int wi = f & 511;
      const int grp = wi >> 6, s2 = wi & 63;
      const int row = (isB ? n0 : gm) + grp * 16 + (s2 >> 2);
      const int k16 = (s2 & 3) ^ ((s2 >> 3) & 3);
      const u16* src = isB ? W1ht : Xb;
      gload16(src + ((size_t)row << 9) + (kt << 5) + k16 * 8,
              &sm[buf][(size_t)f * 8]);
    }
  };

  STAGE(0, 0);
  const int lr = lane & 15;
  const int rI = lr * 4 + ((lane >> 4) ^ ((lr >> 1) & 3));
  for (int kt = 0; kt < 16; ++kt) {
    __syncthreads();
    if (kt + 1 < 16) STAGE((kt + 1) & 1, kt + 1);
    const u16* base = sm[kt & 1];
    short8 bh[4];
#pragma unroll
    for (int j = 0; j < 4; ++j)
      bh[j] = *(const short8*)(base + (size_t)(512 + (wc * 4 + j) * 64 + rI) * 8);
#pragma unroll
    for (int i = 0; i < 4; ++i) {
      short8 ah = *(const short8*)(base + (size_t)((wr * 4 + i) * 64 + rI) * 8);
#pragma unroll
      for (int j = 0; j < 4; ++j)
        acc[i][j] = __builtin_amdgcn_mfma_f32_16x16x32_bf16(ah, bh[j], acc[i][j], 0, 0, 0);
    }
  }

  // ---- epilogue: 4 slabs of 32 rows via fp32 [32][132] + row stats ----
  float* smf = (float*)&sm[0][0];
  const int rr = (lane >> 4) << 2, cc = lane & 15;
  const int lrow = tid >> 3, cg = tid & 7;
#pragma unroll
  for (int s = 0; s < 4; ++s) {
    __syncthreads();
    if (wr == (s >> 1)) {
#pragma unroll
      for (int ii = 0; ii < 2; ++ii) {
        const int i = (s & 1) * 2 + ii;
#pragma unroll
        for (int j = 0; j < 4; ++j)
#pragma unroll
          for (int reg = 0; reg < 4; ++reg)
            smf[(ii * 16 + rr + reg) * 132 + wc * 64 + j * 16 + cc] = acc[i][j][reg];
      }
    }
    __syncthreads();
    const int grow = gm + s * 32 + lrow;
    float s1 = 0.f, ss = 0.f;
    float v[16];
#pragma unroll
    for (int q = 0; q < 4; ++q)
      *(f32x4*)&v[q * 4] = *(const f32x4*)&smf[lrow * 132 + cg * 16 + q * 4];
#pragma unroll
    for (int e = 0; e < 16; ++e) { s1 += v[e]; ss += v[e] * v[e]; }
    unsigned hw2[8];
#pragma unroll
    for (int p = 0; p < 8; ++p) {
      const u16 h0 = f2bf(v[2 * p]), h1 = f2bf(v[2 * p + 1]);
      hw2[p] = (unsigned)h0 | ((unsigned)h1 << 16);
    }
    const size_t o = (size_t)grow * CH + n0 + cg * 16;
    *(uint4*)&Hh[o] = make_uint4(hw2[0], hw2[1], hw2[2], hw2[3]);
    *(uint4*)&Hh[o + 8] = make_uint4(hw2[4], hw2[5], hw2[6], hw2[7]);
#pragma unroll
    for (int m = 1; m <= 4; m <<= 1) { s1 += __shfl_xor(s1, m); ss += __shfl_xor(ss, m); }
    if (cg == 0)
      *(float2*)&STATS[(size_t)grow * 32 + bx * 2] = make_float2(s1, ss);
  }
}

// ---------------------------------------------------------------------------
// K2: reduce 16 slice-partials per row -> (mu, rinv)
// ---------------------------------------------------------------------------
__global__ __launch_bounds__(256) void k_rowstats(const float* __restrict__ STATS,
                                                  float2* __restrict__ MU2) {
  const int row = blockIdx.x * 256 + threadIdx.x;
  float s = 0.f, ss = 0.f;
#pragma unroll
  for (int i = 0; i < 16; ++i) {
    float2 p = *(const float2*)&STATS[((size_t)row << 5) + i * 2];
    s += p.x; ss += p.y;
  }
  const float mu = s * (1.f / CH);
  const float var = ss * (1.f / CH) - mu * mu;
  MU2[row] = make_float2(mu, 1.f / sqrtf(var + 1e-5f));
}

// ---------------------------------------------------------------------------
// K3: fused Z = relu(LN(H)) @ W2 + b2 -> per-head LSE -> Z, EXh, SELF.
// BM=32, BN=256, BK=32, 256 thr (4 waves 1x4, wave tile 32x64), 36KB dbuf
// -> grid 512 = 2 blocks/CU (cross-block overlap hides barrier drains).
// A: tid<128 global->reg->LN->bf16->ds_write; B: all threads gload_lds.
// Chunks/buf: A [0,128), B [128,1152)
// ---------------------------------------------------------------------------
__global__ __launch_bounds__(256) void k_gemm2(const u16* __restrict__ Hh,
                                               const u16* __restrict__ W2ht,
                                               const float* __restrict__ lng, const float* __restrict__ lnb,
                                               const float2* __restrict__ MU2,
                                               const float* __restrict__ b2,
                                               float* __restrict__ Z,
                                               u16* __restrict__ EXh,
                                               float* __restrict__ SELF) {
  __shared__ u16 sm[2][1152 * 8];   // 36 KB
  __shared__ float selfp[32][4];
  const int tid = threadIdx.x;
  const int lane = tid & 63, wc = tid >> 6;   // 4 waves, wave = N-quadrant
  const int gm = blockIdx.x * 32;
  const int st_row = lane >> 2;
  const int st_k16 = (lane & 3) ^ ((lane >> 3) & 3);

  const int arow = tid >> 2, akc = tid & 3;   // valid for tid<128: arow in [0,32)
  const int pcA = (arow >> 4) * 64 + (arow & 15) * 4 + (akc ^ ((arow >> 1) & 3));
  float2 murv = make_float2(0.f, 0.f);
  const u16* gHh = nullptr;
  if (tid < 128) {
    murv = MU2[gm + arow];
    gHh = Hh + ((size_t)(gm + arow) << 11) + akc * 8;
  }

  f32x4 acc[2][4];
#pragma unroll
  for (int i = 0; i < 2; ++i)
#pragma unroll
    for (int j = 0; j < 4; ++j) acc[i][j] = (f32x4){0.f, 0.f, 0.f, 0.f};

  uint4 hwreg;
  auto A_LOAD = [&](int kt) {
    if (tid < 128) hwreg = *(const uint4*)(gHh + kt * 32);
  };
  auto B_STAGE = [&](int buf, int kt) {
#pragma unroll
    for (int t = 0; t < 4; ++t) {
      const int f = t * 256 + tid;            // [0,1024)
      const int grp = f >> 6;
      const int row = grp * 16 + st_row;
      gload16(W2ht + ((size_t)row << 11) + (kt << 5) + st_k16 * 8,
              &sm[buf][(size_t)(128 + f) * 8]);
    }
  };
  auto LN_WRITE = [&](int buf, int kt) {
    if (tid < 128) {
      const int kb = kt * 32 + akc * 8;
      float4 g0 = *(const float4*)&lng[kb];
      float4 g1 = *(const float4*)&lng[kb + 4];
      float4 bb0 = *(const float4*)&lnb[kb];
      float4 bb1 = *(const float4*)&lnb[kb + 4];
      const float gg[8] = {g0.x, g0.y, g0.z, g0.w, g1.x, g1.y, g1.z, g1.w};
      const float bb[8] = {bb0.x, bb0.y, bb0.z, bb0.w, bb1.x, bb1.y, bb1.z, bb1.w};
      const unsigned hws[4] = {hwreg.x, hwreg.y, hwreg.z, hwreg.w};
      unsigned oh[4];
#pragma unroll
      for (int p = 0; p < 4; ++p) {
        u16 yh[2];
#pragma unroll
        for (int e = 0; e < 2; ++e) {
          const float h = bf2f((u16)(hws[p] >> (16 * e)));
          const float a1 = murv.y * gg[2 * p + e];
          const float y = fmaxf(fmaf(h, a1, bb[2 * p + e] - murv.x * a1), 0.f);
          yh[e] = f2bf(y);
        }
        oh[p] = (unsigned)yh[0] | ((unsigned)yh[1] << 16);
      }
      *(uint4*)&sm[buf][(size_t)pcA * 8] = make_uint4(oh[0], oh[1], oh[2], oh[3]);
    }
  };

  const int lr = lane & 15;
  const int rI = lr * 4 + ((lane >> 4) ^ ((lr >> 1) & 3));

  A_LOAD(0);
  B_STAGE(0, 0);
  LN_WRITE(0, 0);

  for (int kt = 0; kt < 64; ++kt) {
    __syncthreads();
    if (kt + 1 < 64) {
      A_LOAD(kt + 1);
      B_STAGE((kt + 1) & 1, kt + 1);
    }
    const u16* base = sm[kt & 1];
    short8 ah[2], bh[4];
#pragma unroll
    for (int i = 0; i < 2; ++i)
      ah[i] = *(const short8*)(base + (i * 64 + rI) * 8);
#pragma unroll
    for (int j = 0; j < 4; ++j)
      bh[j] = *(const short8*)(base + (128 + (wc * 4 + j) * 64 + rI) * 8);
#pragma unroll
    for (int i = 0; i < 2; ++i)
#pragma unroll
      for (int j = 0; j < 4; ++j)
        acc[i][j] = __builtin_amdgcn_mfma_f32_16x16x32_bf16(ah[i], bh[j], acc[i][j], 0, 0, 0);
    if (kt + 1 < 64) LN_WRITE((kt + 1) & 1, kt + 1);
  }

  // fused epilogue: bias + per-head (64-col == this wave's wc) LSE
  const int cc = lane & 15;
  float bias[4];
#pragma unroll
  for (int j = 0; j < 4; ++j) bias[j] = b2[wc * 64 + j * 16 + cc];

#pragma unroll
  for (int i = 0; i < 2; ++i)
#pragma unroll
    for (int reg = 0; reg < 4; ++reg) {
      const int rl = i * 16 + ((lane >> 4) << 2) + reg;   // row in [0,32)
      const int row = gm + rl;
      float z[4];
#pragma unroll
      for (int j = 0; j < 4; ++j) z[j] = acc[i][j][reg] + bias[j];
      float mx = fmaxf(fmaxf(z[0], z[1]), fmaxf(z[2], z[3]));
#pragma unroll
      for (int m = 1; m <= 8; m <<= 1) mx = fmaxf(mx, __shfl_xor(mx, m));
      float se = expf(z[0] - mx) + expf(z[1] - mx) + expf(z[2] - mx) + expf(z[3] - mx);
#pragma unroll
      for (int m = 1; m <= 8; m <<= 1) se += __shfl_xor(se, m);
      const float lse = mx + logf(se);
      float selfc = 0.f;
#pragma unroll
      for (int j = 0; j < 4; ++j) {
        const float p = z[j] - lse;
        const float e = expf(p);
        selfc += e * p;
        const size_t o = (size_t)row * DD + wc * 64 + j * 16 + cc;
        Z[o] = z[j];
        EXh[o] = f2bf(e);
      }
#pragma unroll
      for (int m = 1; m <= 8; m <<= 1) selfc += __shfl_xor(selfc, m);
      if (cc == 0) selfp[rl][wc] = selfc;
    }
  __syncthreads();
  if (tid < 32)
    SELF[gm + tid] = selfp[tid][0] + selfp[tid][1] + selfp[tid][2] + selfp[tid][3];
}

// ---------------------------------------------------------------------------
// K4: LEh = bf16(log(emb)), layout [1024][256]
// ---------------------------------------------------------------------------
__global__ __launch_bounds__(256) void k_prep_le(const float* __restrict__ E,
                                                 u16* __restrict__ LEh) {
  const size_t i = ((size_t)blockIdx.x * 256 + threadIdx.x) * 4;
  float4 v4 = *(const float4*)&E[i];
  const u16 h0 = f2bf(logf(v4.x)), h1 = f2bf(logf(v4.y));
  const u16 h2 = f2bf(logf(v4.z)), h3 = f2bf(logf(v4.w));
  *(uint2*)&LEh[i] = make_uint2((unsigned)h0 | ((unsigned)h1 << 16),
                                (unsigned)h2 | ((unsigned)h3 << 16));
}

// ---------------------------------------------------------------------------
// K5: dots = EX @ LE^T (single bf16 MFMA) with FUSED per-tile argmax.
// 128x128 tile, BK=32, K=256, double-buffered 32KB LDS. PV/PI [N][16].
// XCD-swizzled grid (1024): by=(hw&7)*16+(hw>>6), bx=(hw>>3)&7.
// ---------------------------------------------------------------------------
__global__ __launch_bounds__(256) void k_dots(const u16* __restrict__ EXh,
                                              const u16* __restrict__ LEh,
                                              float* __restrict__ PV, int* __restrict__ PI) {
  __shared__ u16 sm[2][1024 * 8];   // 32 KB
  const int tid = threadIdx.x;
  const int lane = tid & 63, w = tid >> 6;
  const int wr = w >> 1, wc = w & 1;
  const int hw = blockIdx.x;
  const int by = (hw & 7) * 16 + (hw >> 6);   // [0,128)
  const int bx = (hw >> 3) & 7;               // [0,8)
  const int gm = by * 128, m0 = bx * 128;

  f32x4 acc[4][4];
#pragma unroll
  for (int i = 0; i < 4; ++i)
#pragma unroll
    for (int j = 0; j < 4; ++j) acc[i][j] = (f32x4){0.f, 0.f, 0.f, 0.f};

  auto STAGE = [&](int buf, int kt) {
#pragma unroll
    for (int t = 0; t < 4; ++t) {
      const int f = t * 256 + tid;            // [0,1024)
      const int mtx = f >> 9;                 // 0: EX, 1: LE (wave-uniform)
      const int wi = f & 511;
      const int grp = wi >> 6, s2 = wi & 63;
      const int rowbase = mtx ? m0 : gm;
      const int row = rowbase + grp * 16 + (s2 >> 2);
      const int k16 = (s2 & 3) ^ ((s2 >> 3) & 3);
      const u16* src = mtx ? LEh : EXh;
      gload16(src + ((size_t)row << 8) + (kt << 5) + k16 * 8,
              &sm[buf][(size_t)f * 8]);
    }
  };

  STAGE(0, 0);
  const int rI = (lane & 15) * 4 + ((lane >> 4) ^ ((lane >> 1) & 3));
  for (int kt = 0; kt < 8; ++kt) {
    __syncthreads();
    if (kt + 1 < 8) STAGE((kt + 1) & 1, kt + 1);
    const u16* base = sm[kt & 1];
    short8 eh[4], bh[4];
#pragma unroll
    for (int i = 0; i < 4; ++i) {
      eh[i] = *(const short8*)(base + ((wr * 4 + i) * 64 + rI) * 8);
      bh[i] = *(const short8*)(base + (512 + (wc * 4 + i) * 64 + rI) * 8);
    }
#pragma unroll
    for (int i = 0; i < 4; ++i)
#pragma unroll
      for (int j = 0; j < 4; ++j)
        acc[i][j] = __builtin_amdgcn_mfma_f32_16x16x32_bf16(eh[i], bh[j], acc[i][j], 0, 0, 0);
  }

  const int cc = lane & 15;
  const int mtile = bx * 2 + wc;
#pragma unroll
  for (int i = 0; i < 4; ++i)
#pragma unroll
    for (int reg = 0; reg < 4; ++reg) {
      float bv = acc[i][0][reg];
      int bi = m0 + wc * 64 + cc;
#pragma unroll
      for (int j = 1; j < 4; ++j) {
        const float v = acc[i][j][reg];
        if (v > bv) { bv = v; bi = m0 + wc * 64 + j * 16 + cc; }
      }
#pragma unroll
      for (int msk = 8; msk; msk >>= 1) {
        const float ov = __shfl_xor(bv, msk);
        const int   oi = __shfl_xor(bi, msk);
        if (ov > bv || (ov == bv && oi < bi)) { bv = ov; bi = oi; }
      }
      if (cc == 0) {
        const int row = gm + wr * 64 + i * 16 + ((lane >> 4) << 2) + reg;
        PV[row * 16 + mtile] = bv;
        PI[row * 16 + mtile] = bi;
      }
    }
}

// ---------------------------------------------------------------------------
// K6: per row: reduce 16 partials, KL = self - best, gather Q. Wave per row.
// ---------------------------------------------------------------------------
__global__ __launch_bounds__(256) void k_scan(const float* __restrict__ PV,
                                              const int* __restrict__ PI,
                                              const float* __restrict__ SELF,
                                              const float* __restrict__ E,
                                              float* __restrict__ Q,
                                              float* __restrict__ KL) {
  const int tid = threadIdx.x;
  const int lane = tid & 63;
  const int row = blockIdx.x * 4 + (tid >> 6);

  float bv = -1e30f;
  int bi = 0x7fffffff;
  if (lane < 16) { bv = PV[row * 16 + lane]; bi = PI[row * 16 + lane]; }
#pragma unroll
  for (int m = 32; m; m >>= 1) {
    const float ov = __shfl_xor(bv, m);
    const int   oi = __shfl_xor(bi, m);
    if (ov > bv || (ov == bv && oi < bi)) { bv = ov; bi = oi; }
  }
  if (lane == 0) KL[row] = SELF[row] - bv;
  float4 e4 = *(const float4*)&E[((size_t)bi << 8) + lane * 4];
  *(float4*)&Q[((size_t)row << 8) + lane * 4] = e4;
}

// ---------------------------------------------------------------------------
// K7: loss = 0.25/B * sum_n kl[n]*mask[n]
// ---------------------------------------------------------------------------
__global__ __launch_bounds__(256) void k_loss(const float* __restrict__ KL,
                                              const float* __restrict__ MASK,
                                              float* __restrict__ out) {
  __shared__ float red[4];
  const int tid = threadIdx.x;
  float s = 0.f;
  for (int i = tid; i < NROWS; i += 256) s += KL[i] * MASK[i];
#pragma unroll
  for (int m = 32; m; m >>= 1) s += __shfl_xor(s, m);
  if ((tid & 63) == 0) red[tid >> 6] = s;
  __syncthreads();
  if (tid == 0) out[0] = (red[0] + red[1] + red[2] + red[3]) * (0.25f / 16.f);
}

// ---------------------------------------------------------------------------
extern "C" void kernel_launch(void* const* d_in, const int* in_sizes, int n_in,
                              void* d_out, int out_size, void* d_ws, size_t ws_size,
                              hipStream_t stream) {
  const float* x     = (const float*)d_in[0];
  const float* masks = (const float*)d_in[1];
  const float* W1    = (const float*)d_in[2];
  const float* ln_g  = (const float*)d_in[3];
  const float* ln_b  = (const float*)d_in[4];
  const float* W2    = (const float*)d_in[5];
  const float* b2    = (const float*)d_in[6];
  const float* emb   = (const float*)d_in[7];

  float* z_out = (float*)d_out;
  float* q_out = z_out + (size_t)NROWS * DD;
  float* loss_out = z_out + 2 * (size_t)NROWS * DD;

  char* ws = (char*)d_ws;
  u16*   Hh   = (u16*)(ws);                    //  67,108,864 (16384x2048 bf16)
  u16*   W1ht = (u16*)(ws + 67108864);         //   2,097,152
  u16*   W2ht = (u16*)(ws + 69206016);         //   1,048,576
  u16*   LEh  = (u16*)(ws + 70254592);         //     524,288
  float* SELF = (float*)(ws + 70778880);       //      65,536
  float* KL   = (float*)(ws + 70844416);       //      65,536
  float2* MU2 = (float2*)(ws + 70909952);      //     131,072
  u16*   Xb   = (u16*)(ws + 71041024);         //  16,777,216 -> end 87,818,240
  // overlays:
  float* PV   = (float*)(ws);                  //   1 MB (over Hh; H dead after gemm2)
  int*   PI   = (int*)(ws + 1048576);          //   1 MB
  float* STATS = (float*)q_out;                //   2 MB (q_out; consumed before EX written)
  u16*   EXh  = (u16*)q_out;                   //   8 MB (after STATS consumed)

  k_split_x<<<(NROWS * INCH) / 2048, 256, 0, stream>>>(x, Xb);
  k_split_wT<<<dim3(64, 16), 256, 0, stream>>>(W1, W1ht, INCH, CH);
  k_split_wT<<<dim3(8, 64), 256, 0, stream>>>(W2, W2ht, CH, DD);
  k_prep_le<<<256, 256, 0, stream>>>(emb, LEh);

  k_gemm1<<<2048, 256, 0, stream>>>(Xb, W1ht, Hh, STATS);
  k_rowstats<<<NROWS / 256, 256, 0, stream>>>(STATS, MU2);
  k_gemm2<<<NROWS / 32, 256, 0, stream>>>(Hh, W2ht, ln_g, ln_b, MU2, b2,
                                          z_out, EXh, SELF);

  k_dots<<<1024, 256, 0, stream>>>(EXh, LEh, PV, PI);
  k_scan<<<4096, 256, 0, stream>>>(PV, PI, SELF, emb, q_out, KL);
  k_loss<<<1, 256, 0, stream>>>(KL, masks, loss_out);
}

// Round 17
// 200.121 us; speedup vs baseline: 1.0324x; 1.0324x over previous
//
#include <hip/hip_runtime.h>
#include <math.h>

#define NROWS 16384   // B*T
#define INCH  512
#define CH    2048
#define DD    256
#define MM    1024

typedef unsigned short u16;
typedef short short8 __attribute__((ext_vector_type(8)));
typedef float f32x4 __attribute__((ext_vector_type(4)));

__device__ __forceinline__ u16 f2bf(float f) {
  unsigned u = __float_as_uint(f);
  return (u16)((u + 0x7fffu + ((u >> 16) & 1u)) >> 16);
}
__device__ __forceinline__ float bf2f(u16 h) {
  return __uint_as_float(((unsigned)h) << 16);
}
__device__ __forceinline__ void gload16(const u16* g, u16* lds) {
  __builtin_amdgcn_global_load_lds((const __attribute__((address_space(1))) void*)g,
                                   (__attribute__((address_space(3))) void*)lds, 16, 0, 0);
}

// Coalesced-staging chunk mapping (16B chunks of 8 bf16 along K):
//   PC(row,kc) = (row>>4)*64 + (row&15)*4 + (kc ^ ((row>>1)&3))
//   frag read: chunk = group*64 + rI, rI = (lane&15)*4 + ((lane>>4)^((lane>>1)&3))

// ---------------------------------------------------------------------------
// K0: X fp32 -> bf16 (row-major, each element converted exactly once)
// ---------------------------------------------------------------------------
__global__ __launch_bounds__(256) void k_split_x(const float* __restrict__ x,
                                                 u16* __restrict__ xb) {
  const size_t i = ((size_t)blockIdx.x * 256 + threadIdx.x) * 8;
  float4 a = *(const float4*)(x + i);
  float4 b = *(const float4*)(x + i + 4);
  float v[8] = {a.x, a.y, a.z, a.w, b.x, b.y, b.z, b.w};
  unsigned hw[4];
#pragma unroll
  for (int p = 0; p < 4; ++p)
    hw[p] = (unsigned)f2bf(v[2 * p]) | ((unsigned)f2bf(v[2 * p + 1]) << 16);
  *(uint4*)(xb + i) = make_uint4(hw[0], hw[1], hw[2], hw[3]);
}

// src [R][C] fp32  ->  d [C][R] bf16 (transpose + round)
__global__ __launch_bounds__(256) void k_split_wT(const float* __restrict__ src,
                                                  u16* __restrict__ dh, int R, int C) {
  __shared__ float t[32][33];
  const int tx = threadIdx.x & 31, ty = threadIdx.x >> 5;
  const int c0 = blockIdx.x * 32, r0 = blockIdx.y * 32;
#pragma unroll
  for (int i = 0; i < 4; ++i)
    t[ty + i * 8][tx] = src[(size_t)(r0 + ty + i * 8) * C + c0 + tx];
  __syncthreads();
#pragma unroll
  for (int i = 0; i < 4; ++i) {
    float v = t[tx][ty + i * 8];
    dh[(size_t)(c0 + ty + i * 8) * R + r0 + tx] = f2bf(v);
  }
}

// ---------------------------------------------------------------------------
// K1: H = bf16(Xb @ W1).  128x128 tile, BK=32, 4 waves (2x2), 32KB dbuf LDS.
// Both operands via global_load_lds. XCD-swizzled grid (2048).
// ---------------------------------------------------------------------------
__global__ __launch_bounds__(256) void k_gemm1(const u16* __restrict__ Xb,
                                               const u16* __restrict__ W1ht,
                                               u16* __restrict__ Hh,
                                               float* __restrict__ STATS) {
  __shared__ u16 sm[2][1024 * 8];   // 32 KB
  const int tid = threadIdx.x;
  const int lane = tid & 63, w = tid >> 6;
  const int wr = w >> 1, wc = w & 1;
  const int hw = blockIdx.x;
  const int u = hw >> 3;
  const int by = (hw & 7) * 16 + (u >> 4);   // [0,128)
  const int bx = u & 15;                     // [0,16)
  const int gm = by * 128, n0 = bx * 128;

  f32x4 acc[4][4];
#pragma unroll
  for (int i = 0; i < 4; ++i)
#pragma unroll
    for (int j = 0; j < 4; ++j) acc[i][j] = (f32x4){0.f, 0.f, 0.f, 0.f};

  auto STAGE = [&](int buf, int kt) {
#pragma unroll
    for (int t = 0; t < 4; ++t) {
      const int f = t * 256 + tid;            // [0,1024)
      const int isB = f >> 9;                 // wave-uniform
      const int wi = f & 511;
      const int grp = wi >> 6, s2 = wi & 63;
      const int row = (isB ? n0 : gm) + grp * 16 + (s2 >> 2);
      const int k16 = (s2 & 3) ^ ((s2 >> 3) & 3);
      const u16* src = isB ? W1ht : Xb;
      gload16(src + ((size_t)row << 9) + (kt << 5) + k16 * 8,
              &sm[buf][(size_t)f * 8]);
    }
  };

  STAGE(0, 0);
  const int lr = lane & 15;
  const int rI = lr * 4 + ((lane >> 4) ^ ((lr >> 1) & 3));
  for (int kt = 0; kt < 16; ++kt) {
    __syncthreads();
    if (kt + 1 < 16) STAGE((kt + 1) & 1, kt + 1);
    const u16* base = sm[kt & 1];
    short8 bh[4];
#pragma unroll
    for (int j = 0; j < 4; ++j)
      bh[j] = *(const short8*)(base + (size_t)(512 + (wc * 4 + j) * 64 + rI) * 8);
#pragma unroll
    for (int i = 0; i < 4; ++i) {
      short8 ah = *(const short8*)(base + (size_t)((wr * 4 + i) * 64 + rI) * 8);
#pragma unroll
      for (int j = 0; j < 4; ++j)
        acc[i][j] = __builtin_amdgcn_mfma_f32_16x16x32_bf16(ah, bh[j], acc[i][j], 0, 0, 0);
    }
  }

  // ---- epilogue: 4 slabs of 32 rows via fp32 [32][132] + row stats ----
  float* smf = (float*)&sm[0][0];
  const int rr = (lane >> 4) << 2, cc = lane & 15;
  const int lrow = tid >> 3, cg = tid & 7;
#pragma unroll
  for (int s = 0; s < 4; ++s) {
    __syncthreads();
    if (wr == (s >> 1)) {
#pragma unroll
      for (int ii = 0; ii < 2; ++ii) {
        const int i = (s & 1) * 2 + ii;
#pragma unroll
        for (int j = 0; j < 4; ++j)
#pragma unroll
          for (int reg = 0; reg < 4; ++reg)
            smf[(ii * 16 + rr + reg) * 132 + wc * 64 + j * 16 + cc] = acc[i][j][reg];
      }
    }
    __syncthreads();
    const int grow = gm + s * 32 + lrow;
    float s1 = 0.f, ss = 0.f;
    float v[16];
#pragma unroll
    for (int q = 0; q < 4; ++q)
      *(f32x4*)&v[q * 4] = *(const f32x4*)&smf[lrow * 132 + cg * 16 + q * 4];
#pragma unroll
    for (int e = 0; e < 16; ++e) { s1 += v[e]; ss += v[e] * v[e]; }
    unsigned hw2[8];
#pragma unroll
    for (int p = 0; p < 8; ++p) {
      const u16 h0 = f2bf(v[2 * p]), h1 = f2bf(v[2 * p + 1]);
      hw2[p] = (unsigned)h0 | ((unsigned)h1 << 16);
    }
    const size_t o = (size_t)grow * CH + n0 + cg * 16;
    *(uint4*)&Hh[o] = make_uint4(hw2[0], hw2[1], hw2[2], hw2[3]);
    *(uint4*)&Hh[o + 8] = make_uint4(hw2[4], hw2[5], hw2[6], hw2[7]);
#pragma unroll
    for (int m = 1; m <= 4; m <<= 1) { s1 += __shfl_xor(s1, m); ss += __shfl_xor(ss, m); }
    if (cg == 0)
      *(float2*)&STATS[(size_t)grow * 32 + bx * 2] = make_float2(s1, ss);
  }
}

// ---------------------------------------------------------------------------
// K2: reduce 16 slice-partials per row -> (mu, rinv)
// ---------------------------------------------------------------------------
__global__ __launch_bounds__(256) void k_rowstats(const float* __restrict__ STATS,
                                                  float2* __restrict__ MU2) {
  const int row = blockIdx.x * 256 + threadIdx.x;
  float s = 0.f, ss = 0.f;
#pragma unroll
  for (int i = 0; i < 16; ++i) {
    float2 p = *(const float2*)&STATS[((size_t)row << 5) + i * 2];
    s += p.x; ss += p.y;
  }
  const float mu = s * (1.f / CH);
  const float var = ss * (1.f / CH) - mu * mu;
  MU2[row] = make_float2(mu, 1.f / sqrtf(var + 1e-5f));
}

// ---------------------------------------------------------------------------
// K3: fused Z = relu(LN(H)) @ W2 + b2 -> per-head LSE -> Z, EXh, SELF2.
// BM=64, BN=128 (B-tile split with the grid: no W2 duplication), BK=32,
// 256 thr (4 waves 2x2, wave 32 rows x 64 cols = one head), 24KB dbuf LDS,
// grid (256,2) = 512 blocks = 2 blocks/CU.
// BOTH operands staged via global_load_lds (raw H); LN+ReLU applied
// IN-REGISTER on A fragments after ds_read (mu hoisted per lane-row).
// Chunks/buf: A [0,256), B [256,768)
// ---------------------------------------------------------------------------
__global__ __launch_bounds__(256) void k_gemm2(const u16* __restrict__ Hh,
                                               const u16* __restrict__ W2ht,
                                               const float* __restrict__ lng, const float* __restrict__ lnb,
                                               const float2* __restrict__ MU2,
                                               const float* __restrict__ b2,
                                               float* __restrict__ Z,
                                               u16* __restrict__ EXh,
                                               float* __restrict__ SELF2) {
  __shared__ u16 sm[2][768 * 8];   // 24 KB
  __shared__ float selfp[64][2];
  const int tid = threadIdx.x;
  const int lane = tid & 63, w = tid >> 6;
  const int wr = w >> 1, wc = w & 1;
  const int gm = blockIdx.x * 64;
  const int n0 = blockIdx.y * 128;          // W2ht row base (output cols)

  auto STAGE = [&](int buf, int kt) {
#pragma unroll
    for (int t = 0; t < 3; ++t) {
      const int f = t * 256 + tid;            // [0,768)
      const int isB = (f >= 256);             // wave-uniform (t-granular)
      const int wi = isB ? (f - 256) : f;
      const int grp = wi >> 6, s2 = wi & 63;
      const int row = (isB ? n0 : gm) + grp * 16 + (s2 >> 2);
      const int k16 = (s2 & 3) ^ ((s2 >> 3) & 3);
      const u16* src = isB ? W2ht : Hh;
      gload16(src + ((size_t)row << 11) + (kt << 5) + k16 * 8,
              &sm[buf][(size_t)f * 8]);
    }
  };

  f32x4 acc[2][4];
#pragma unroll
  for (int i = 0; i < 2; ++i)
#pragma unroll
    for (int j = 0; j < 4; ++j) acc[i][j] = (f32x4){0.f, 0.f, 0.f, 0.f};

  const int lr = lane & 15, kc2 = lane >> 4;
  const int rI = lr * 4 + (kc2 ^ ((lr >> 1) & 3));
  // LN constants per lane (rows fixed: wr*32 + i*16 + lr)
  const float2 mrow[2] = {MU2[gm + wr * 32 + lr], MU2[gm + wr * 32 + 16 + lr]};

  STAGE(0, 0);
  for (int kt = 0; kt < 64; ++kt) {
    __syncthreads();
    if (kt + 1 < 64) STAGE((kt + 1) & 1, kt + 1);
    const u16* base = sm[kt & 1];
    // raw A fragments + B fragments
    short8 ar[2], bh[4];
#pragma unroll
    for (int i = 0; i < 2; ++i)
      ar[i] = *(const short8*)(base + ((wr * 2 + i) * 64 + rI) * 8);
#pragma unroll
    for (int j = 0; j < 4; ++j)
      bh[j] = *(const short8*)(base + (256 + (wc * 4 + j) * 64 + rI) * 8);
    // in-register LN+ReLU+round on A
    const int kb = kt * 32 + kc2 * 8;
    float4 g0 = *(const float4*)&lng[kb];
    float4 g1 = *(const float4*)&lng[kb + 4];
    float4 b0 = *(const float4*)&lnb[kb];
    float4 b1 = *(const float4*)&lnb[kb + 4];
    const float gg[8] = {g0.x, g0.y, g0.z, g0.w, g1.x, g1.y, g1.z, g1.w};
    const float bb[8] = {b0.x, b0.y, b0.z, b0.w, b1.x, b1.y, b1.z, b1.w};
    short8 ah[2];
#pragma unroll
    for (int i = 0; i < 2; ++i) {
      const float2 mu = mrow[i];
#pragma unroll
      for (int e = 0; e < 8; ++e) {
        const float h = bf2f((u16)ar[i][e]);
        const float a1 = mu.y * gg[e];
        const float y = fmaxf(fmaf(h, a1, bb[e] - mu.x * a1), 0.f);
        ah[i][e] = (short)f2bf(y);
      }
    }
#pragma unroll
    for (int i = 0; i < 2; ++i)
#pragma unroll
      for (int j = 0; j < 4; ++j)
        acc[i][j] = __builtin_amdgcn_mfma_f32_16x16x32_bf16(ah[i], bh[j], acc[i][j], 0, 0, 0);
  }

  // fused epilogue: bias + per-head (64-col == this wave's wc) LSE
  const int cc = lane & 15;
  float bias[4];
#pragma unroll
  for (int j = 0; j < 4; ++j) bias[j] = b2[n0 + wc * 64 + j * 16 + cc];

#pragma unroll
  for (int i = 0; i < 2; ++i)
#pragma unroll
    for (int reg = 0; reg < 4; ++reg) {
      const int rl = wr * 32 + i * 16 + ((lane >> 4) << 2) + reg;   // row in [0,64)
      const int row = gm + rl;
      float z[4];
#pragma unroll
      for (int j = 0; j < 4; ++j) z[j] = acc[i][j][reg] + bias[j];
      float mx = fmaxf(fmaxf(z[0], z[1]), fmaxf(z[2], z[3]));
#pragma unroll
      for (int m = 1; m <= 8; m <<= 1) mx = fmaxf(mx, __shfl_xor(mx, m));
      float se = expf(z[0] - mx) + expf(z[1] - mx) + expf(z[2] - mx) + expf(z[3] - mx);
#pragma unroll
      for (int m = 1; m <= 8; m <<= 1) se += __shfl_xor(se, m);
      const float lse = mx + logf(se);
      float selfc = 0.f;
#pragma unroll
      for (int j = 0; j < 4; ++j) {
        const float p = z[j] - lse;
        const float e = expf(p);
        selfc += e * p;
        const size_t o = (size_t)row * DD + n0 + wc * 64 + j * 16 + cc;
        Z[o] = z[j];
        EXh[o] = f2bf(e);
      }
#pragma unroll
      for (int m = 1; m <= 8; m <<= 1) selfc += __shfl_xor(selfc, m);
      if (cc == 0) selfp[rl][wc] = selfc;
    }
  __syncthreads();
  if (tid < 64)
    SELF2[(size_t)(gm + tid) * 2 + blockIdx.y] = selfp[tid][0] + selfp[tid][1];
}

// ---------------------------------------------------------------------------
// K4: LEh = bf16(log(emb)), layout [1024][256]
// ---------------------------------------------------------------------------
__global__ __launch_bounds__(256) void k_prep_le(const float* __restrict__ E,
                                                 u16* __restrict__ LEh) {
  const size_t i = ((size_t)blockIdx.x * 256 + threadIdx.x) * 4;
  float4 v4 = *(const float4*)&E[i];
  const u16 h0 = f2bf(logf(v4.x)), h1 = f2bf(logf(v4.y));
  const u16 h2 = f2bf(logf(v4.z)), h3 = f2bf(logf(v4.w));
  *(uint2*)&LEh[i] = make_uint2((unsigned)h0 | ((unsigned)h1 << 16),
                                (unsigned)h2 | ((unsigned)h3 << 16));
}

// ---------------------------------------------------------------------------
// K5: dots = EX @ LE^T (single bf16 MFMA) with FUSED per-tile argmax.
// 128x128 tile, BK=32, K=256, double-buffered 32KB LDS. PV/PI [N][16].
// XCD-swizzled grid (1024): by=(hw&7)*16+(hw>>6), bx=(hw>>3)&7.
// ---------------------------------------------------------------------------
__global__ __launch_bounds__(256) void k_dots(const u16* __restrict__ EXh,
                                              const u16* __restrict__ LEh,
                                              float* __restrict__ PV, int* __restrict__ PI) {
  __shared__ u16 sm[2][1024 * 8];   // 32 KB
  const int tid = threadIdx.x;
  const int lane = tid & 63, w = tid >> 6;
  const int wr = w >> 1, wc = w & 1;
  const int hw = blockIdx.x;
  const int by = (hw & 7) * 16 + (hw >> 6);   // [0,128)
  const int bx = (hw >> 3) & 7;               // [0,8)
  const int gm = by * 128, m0 = bx * 128;

  f32x4 acc[4][4];
#pragma unroll
  for (int i = 0; i < 4; ++i)
#pragma unroll
    for (int j = 0; j < 4; ++j) acc[i][j] = (f32x4){0.f, 0.f, 0.f, 0.f};

  auto STAGE = [&](int buf, int kt) {
#pragma unroll
    for (int t = 0; t < 4; ++t) {
      const int f = t * 256 + tid;            // [0,1024)
      const int mtx = f >> 9;                 // 0: EX, 1: LE (wave-uniform)
      const int wi = f & 511;
      const int grp = wi >> 6, s2 = wi & 63;
      const int rowbase = mtx ? m0 : gm;
      const int row = rowbase + grp * 16 + (s2 >> 2);
      const int k16 = (s2 & 3) ^ ((s2 >> 3) & 3);
      const u16* src = mtx ? LEh : EXh;
      gload16(src + ((size_t)row << 8) + (kt << 5) + k16 * 8,
              &sm[buf][(size_t)f * 8]);
    }
  };

  STAGE(0, 0);
  const int rI = (lane & 15) * 4 + ((lane >> 4) ^ ((lane >> 1) & 3));
  for (int kt = 0; kt < 8; ++kt) {
    __syncthreads();
    if (kt + 1 < 8) STAGE((kt + 1) & 1, kt + 1);
    const u16* base = sm[kt & 1];
    short8 eh[4], bh[4];
#pragma unroll
    for (int i = 0; i < 4; ++i) {
      eh[i] = *(const short8*)(base + ((wr * 4 + i) * 64 + rI) * 8);
      bh[i] = *(const short8*)(base + (512 + (wc * 4 + i) * 64 + rI) * 8);
    }
#pragma unroll
    for (int i = 0; i < 4; ++i)
#pragma unroll
      for (int j = 0; j < 4; ++j)
        acc[i][j] = __builtin_amdgcn_mfma_f32_16x16x32_bf16(eh[i], bh[j], acc[i][j], 0, 0, 0);
  }

  const int cc = lane & 15;
  const int mtile = bx * 2 + wc;
#pragma unroll
  for (int i = 0; i < 4; ++i)
#pragma unroll
    for (int reg = 0; reg < 4; ++reg) {
      float bv = acc[i][0][reg];
      int bi = m0 + wc * 64 + cc;
#pragma unroll
      for (int j = 1; j < 4; ++j) {
        const float v = acc[i][j][reg];
        if (v > bv) { bv = v; bi = m0 + wc * 64 + j * 16 + cc; }
      }
#pragma unroll
      for (int msk = 8; msk; msk >>= 1) {
        const float ov = __shfl_xor(bv, msk);
        const int   oi = __shfl_xor(bi, msk);
        if (ov > bv || (ov == bv && oi < bi)) { bv = ov; bi = oi; }
      }
      if (cc == 0) {
        const int row = gm + wr * 64 + i * 16 + ((lane >> 4) << 2) + reg;
        PV[row * 16 + mtile] = bv;
        PI[row * 16 + mtile] = bi;
      }
    }
}

// ---------------------------------------------------------------------------
// K6: per row: reduce 16 partials, KL = self - best, gather Q. Wave per row.
// ---------------------------------------------------------------------------
__global__ __launch_bounds__(256) void k_scan(const float* __restrict__ PV,
                                              const int* __restrict__ PI,
                                              const float* __restrict__ SELF2,
                                              const float* __restrict__ E,
                                              float* __restrict__ Q,
                                              float* __restrict__ KL) {
  const int tid = threadIdx.x;
  const int lane = tid & 63;
  const int row = blockIdx.x * 4 + (tid >> 6);

  float bv = -1e30f;
  int bi = 0x7fffffff;
  if (lane < 16) { bv = PV[row * 16 + lane]; bi = PI[row * 16 + lane]; }
#pragma unroll
  for (int m = 32; m; m >>= 1) {
    const float ov = __shfl_xor(bv, m);
    const int   oi = __shfl_xor(bi, m);
    if (ov > bv || (ov == bv && oi < bi)) { bv = ov; bi = oi; }
  }
  if (lane == 0) KL[row] = SELF2[(size_t)row * 2] + SELF2[(size_t)row * 2 + 1] - bv;
  float4 e4 = *(const float4*)&E[((size_t)bi << 8) + lane * 4];
  *(float4*)&Q[((size_t)row << 8) + lane * 4] = e4;
}

// ---------------------------------------------------------------------------
// K7: loss = 0.25/B * sum_n kl[n]*mask[n]
// ---------------------------------------------------------------------------
__global__ __launch_bounds__(256) void k_loss(const float* __restrict__ KL,
                                              const float* __restrict__ MASK,
                                              float* __restrict__ out) {
  __shared__ float red[4];
  const int tid = threadIdx.x;
  float s = 0.f;
  for (int i = tid; i < NROWS; i += 256) s += KL[i] * MASK[i];
#pragma unroll
  for (int m = 32; m; m >>= 1) s += __shfl_xor(s, m);
  if ((tid & 63) == 0) red[tid >> 6] = s;
  __syncthreads();
  if (tid == 0) out[0] = (red[0] + red[1] + red[2] + red[3]) * (0.25f / 16.f);
}

// ---------------------------------------------------------------------------
extern "C" void kernel_launch(void* const* d_in, const int* in_sizes, int n_in,
                              void* d_out, int out_size, void* d_ws, size_t ws_size,
                              hipStream_t stream) {
  const float* x     = (const float*)d_in[0];
  const float* masks = (const float*)d_in[1];
  const float* W1    = (const float*)d_in[2];
  const float* ln_g  = (const float*)d_in[3];
  const float* ln_b  = (const float*)d_in[4];
  const float* W2    = (const float*)d_in[5];
  const float* b2    = (const float*)d_in[6];
  const float* emb   = (const float*)d_in[7];

  float* z_out = (float*)d_out;
  float* q_out = z_out + (size_t)NROWS * DD;
  float* loss_out = z_out + 2 * (size_t)NROWS * DD;

  char* ws = (char*)d_ws;
  u16*   Hh    = (u16*)(ws);                   //  67,108,864 (16384x2048 bf16)
  u16*   W1ht  = (u16*)(ws + 67108864);        //   2,097,152
  u16*   W2ht  = (u16*)(ws + 69206016);        //   1,048,576
  u16*   LEh   = (u16*)(ws + 70254592);        //     524,288
  float* SELF2 = (float*)(ws + 70778880);      //     131,072
  float* KL    = (float*)(ws + 70909952);      //      65,536
  float2* MU2  = (float2*)(ws + 70975488);     //     131,072
  u16*   Xb    = (u16*)(ws + 71106560);        //  16,777,216 -> end 87,883,776
  // overlays:
  float* PV    = (float*)(ws);                 //   1 MB (over Hh; H dead after gemm2)
  int*   PI    = (int*)(ws + 1048576);         //   1 MB
  float* STATS = (float*)q_out;                //   2 MB (q_out; consumed before EX written)
  u16*   EXh   = (u16*)q_out;                  //   8 MB (after STATS consumed)

  k_split_x<<<(NROWS * INCH) / 2048, 256, 0, stream>>>(x, Xb);
  k_split_wT<<<dim3(64, 16), 256, 0, stream>>>(W1, W1ht, INCH, CH);
  k_split_wT<<<dim3(8, 64), 256, 0, stream>>>(W2, W2ht, CH, DD);
  k_prep_le<<<256, 256, 0, stream>>>(emb, LEh);

  k_gemm1<<<2048, 256, 0, stream>>>(Xb, W1ht, Hh, STATS);
  k_rowstats<<<NROWS / 256, 256, 0, stream>>>(STATS, MU2);
  k_gemm2<<<dim3(NROWS / 64, 2), 256, 0, stream>>>(Hh, W2ht, ln_g, ln_b, MU2, b2,
                                                   z_out, EXh, SELF2);

  k_dots<<<1024, 256, 0, stream>>>(EXh, LEh, PV, PI);
  k_scan<<<4096, 256, 0, stream>>>(PV, PI, SELF2, emb, q_out, KL);
  k_loss<<<1, 256, 0, stream>>>(KL, masks, loss_out);
}

// Round 18
// 185.534 us; speedup vs baseline: 1.1135x; 1.0786x over previous
//
#include <hip/hip_runtime.h>
#include <math.h>

#define NROWS 16384   // B*T
#define INCH  512
#define CH    2048
#define DD    256
#define MM    1024

typedef unsigned short u16;
typedef short short8 __attribute__((ext_vector_type(8)));
typedef float f32x4 __attribute__((ext_vector_type(4)));

__device__ __forceinline__ u16 f2bf(float f) {
  unsigned u = __float_as_uint(f);
  return (u16)((u + 0x7fffu + ((u >> 16) & 1u)) >> 16);
}
__device__ __forceinline__ float bf2f(u16 h) {
  return __uint_as_float(((unsigned)h) << 16);
}
__device__ __forceinline__ void gload16(const u16* g, u16* lds) {
  __builtin_amdgcn_global_load_lds((const __attribute__((address_space(1))) void*)g,
                                   (__attribute__((address_space(3))) void*)lds, 16, 0, 0);
}

// Coalesced-staging chunk mapping (16B chunks of 8 bf16 along K):
//   PC(row,kc) = (row>>4)*64 + (row&15)*4 + (kc ^ ((row>>1)&3))
//   frag read: chunk = group*64 + rI, rI = (lane&15)*4 + ((lane>>4)^((lane>>1)&3))

// ---------------------------------------------------------------------------
// K0: X fp32 -> bf16 (row-major, each element converted exactly once)
// ---------------------------------------------------------------------------
__global__ __launch_bounds__(256) void k_split_x(const float* __restrict__ x,
                                                 u16* __restrict__ xb) {
  const size_t i = ((size_t)blockIdx.x * 256 + threadIdx.x) * 8;
  float4 a = *(const float4*)(x + i);
  float4 b = *(const float4*)(x + i + 4);
  float v[8] = {a.x, a.y, a.z, a.w, b.x, b.y, b.z, b.w};
  unsigned hw[4];
#pragma unroll
  for (int p = 0; p < 4; ++p)
    hw[p] = (unsigned)f2bf(v[2 * p]) | ((unsigned)f2bf(v[2 * p + 1]) << 16);
  *(uint4*)(xb + i) = make_uint4(hw[0], hw[1], hw[2], hw[3]);
}

// src [R][C] fp32  ->  d [C][R] bf16 (transpose + round)
__global__ __launch_bounds__(256) void k_split_wT(const float* __restrict__ src,
                                                  u16* __restrict__ dh, int R, int C) {
  __shared__ float t[32][33];
  const int tx = threadIdx.x & 31, ty = threadIdx.x >> 5;
  const int c0 = blockIdx.x * 32, r0 = blockIdx.y * 32;
#pragma unroll
  for (int i = 0; i < 4; ++i)
    t[ty + i * 8][tx] = src[(size_t)(r0 + ty + i * 8) * C + c0 + tx];
  __syncthreads();
#pragma unroll
  for (int i = 0; i < 4; ++i) {
    float v = t[tx][ty + i * 8];
    dh[(size_t)(c0 + ty + i * 8) * R + r0 + tx] = f2bf(v);
  }
}

// ---------------------------------------------------------------------------
// K1: H = bf16(Xb @ W1).  128x128 tile, BK=32, 4 waves (2x2), 32KB dbuf LDS.
// Both operands via global_load_lds. XCD-swizzled grid (2048).
// ---------------------------------------------------------------------------
__global__ __launch_bounds__(256) void k_gemm1(const u16* __restrict__ Xb,
                                               const u16* __restrict__ W1ht,
                                               u16* __restrict__ Hh,
                                               float* __restrict__ STATS) {
  __shared__ u16 sm[2][1024 * 8];   // 32 KB
  const int tid = threadIdx.x;
  const int lane = tid & 63, w = tid >> 6;
  const int wr = w >> 1, wc = w & 1;
  const int hw = blockIdx.x;
  const int u = hw >> 3;
  const int by = (hw & 7) * 16 + (u >> 4);   // [0,128)
  const int bx = u & 15;                     // [0,16)
  const int gm = by * 128, n0 = bx * 128;

  f32x4 acc[4][4];
#pragma unroll
  for (int i = 0; i < 4; ++i)
#pragma unroll
    for (int j = 0; j < 4; ++j) acc[i][j] = (f32x4){0.f, 0.f, 0.f, 0.f};

  auto STAGE = [&](int buf, int kt) {
#pragma unroll
    for (int t = 0; t < 4; ++t) {
      const int f = t * 256 + tid;            // [0,1024)
      const int isB = f >> 9;                 // wave-uniform
      const int wi = f & 511;
      const int grp = wi >> 6, s2 = wi & 63;
      const int row = (isB ? n0 : gm) + grp * 16 + (s2 >> 2);
      const int k16 = (s2 & 3) ^ ((s2 >> 3) & 3);
      const u16* src = isB ? W1ht : Xb;
      gload16(src + ((size_t)row << 9) + (kt << 5) + k16 * 8,
              &sm[buf][(size_t)f * 8]);
    }
  };

  STAGE(0, 0);
  const int lr = lane & 15;
  const int rI = lr * 4 + ((lane >> 4) ^ ((lr >> 1) & 3));
  for (int kt = 0; kt < 16; ++kt) {
    __syncthreads();
    if (kt + 1 < 16) STAGE((kt + 1) & 1, kt + 1);
    const u16* base = sm[kt & 1];
    short8 bh[4];
#pragma unroll
    for (int j = 0; j < 4; ++j)
      bh[j] = *(const short8*)(base + (size_t)(512 + (wc * 4 + j) * 64 + rI) * 8);
#pragma unroll
    for (int i = 0; i < 4; ++i) {
      short8 ah = *(const short8*)(base + (size_t)((wr * 4 + i) * 64 + rI) * 8);
#pragma unroll
      for (int j = 0; j < 4; ++j)
        acc[i][j] = __builtin_amdgcn_mfma_f32_16x16x32_bf16(ah, bh[j], acc[i][j], 0, 0, 0);
    }
  }

  // ---- epilogue: 4 slabs of 32 rows via fp32 [32][132] + row stats ----
  float* smf = (float*)&sm[0][0];
  const int rr = (lane >> 4) << 2, cc = lane & 15;
  const int lrow = tid >> 3, cg = tid & 7;
#pragma unroll
  for (int s = 0; s < 4; ++s) {
    __syncthreads();
    if (wr == (s >> 1)) {
#pragma unroll
      for (int ii = 0; ii < 2; ++ii) {
        const int i = (s & 1) * 2 + ii;
#pragma unroll
        for (int j = 0; j < 4; ++j)
#pragma unroll
          for (int reg = 0; reg < 4; ++reg)
            smf[(ii * 16 + rr + reg) * 132 + wc * 64 + j * 16 + cc] = acc[i][j][reg];
      }
    }
    __syncthreads();
    const int grow = gm + s * 32 + lrow;
    float s1 = 0.f, ss = 0.f;
    float v[16];
#pragma unroll
    for (int q = 0; q < 4; ++q)
      *(f32x4*)&v[q * 4] = *(const f32x4*)&smf[lrow * 132 + cg * 16 + q * 4];
#pragma unroll
    for (int e = 0; e < 16; ++e) { s1 += v[e]; ss += v[e] * v[e]; }
    unsigned hw2[8];
#pragma unroll
    for (int p = 0; p < 8; ++p) {
      const u16 h0 = f2bf(v[2 * p]), h1 = f2bf(v[2 * p + 1]);
      hw2[p] = (unsigned)h0 | ((unsigned)h1 << 16);
    }
    const size_t o = (size_t)grow * CH + n0 + cg * 16;
    *(uint4*)&Hh[o] = make_uint4(hw2[0], hw2[1], hw2[2], hw2[3]);
    *(uint4*)&Hh[o + 8] = make_uint4(hw2[4], hw2[5], hw2[6], hw2[7]);
#pragma unroll
    for (int m = 1; m <= 4; m <<= 1) { s1 += __shfl_xor(s1, m); ss += __shfl_xor(ss, m); }
    if (cg == 0)
      *(float2*)&STATS[(size_t)grow * 32 + bx * 2] = make_float2(s1, ss);
  }
}

// ---------------------------------------------------------------------------
// K2: LN+ReLU in place on H (bf16). One block per row; absorbs rowstats.
// Memory-bound 128MB. Same math as the previous fused-LN path (bitwise).
// ---------------------------------------------------------------------------
__global__ __launch_bounds__(256) void k_ln(u16* __restrict__ Hh,
                                            const float* __restrict__ STATS,
                                            const float* __restrict__ lng,
                                            const float* __restrict__ lnb) {
  const int row = blockIdx.x;
  const int tid = threadIdx.x;
  float s = 0.f, ss = 0.f;
#pragma unroll
  for (int i = 0; i < 16; ++i) {
    float2 p = *(const float2*)&STATS[((size_t)row << 5) + i * 2];
    s += p.x; ss += p.y;
  }
  const float mu = s * (1.f / CH);
  const float var = ss * (1.f / CH) - mu * mu;
  const float rinv = 1.f / sqrtf(var + 1e-5f);

  const int kb = tid * 8;
  uint4* hp = (uint4*)(Hh + (size_t)row * CH + kb);
  uint4 hv = *hp;
  float4 g0 = *(const float4*)&lng[kb];
  float4 g1 = *(const float4*)&lng[kb + 4];
  float4 b0 = *(const float4*)&lnb[kb];
  float4 b1 = *(const float4*)&lnb[kb + 4];
  const float gg[8] = {g0.x, g0.y, g0.z, g0.w, g1.x, g1.y, g1.z, g1.w};
  const float bb[8] = {b0.x, b0.y, b0.z, b0.w, b1.x, b1.y, b1.z, b1.w};
  const unsigned hws[4] = {hv.x, hv.y, hv.z, hv.w};
  unsigned oh[4];
#pragma unroll
  for (int p = 0; p < 4; ++p) {
    u16 yh[2];
#pragma unroll
    for (int e = 0; e < 2; ++e) {
      const float h = bf2f((u16)(hws[p] >> (16 * e)));
      const float a1 = rinv * gg[2 * p + e];
      const float y = fmaxf(fmaf(h, a1, bb[2 * p + e] - mu * a1), 0.f);
      yh[e] = f2bf(y);
    }
    oh[p] = (unsigned)yh[0] | ((unsigned)yh[1] << 16);
  }
  *hp = make_uint4(oh[0], oh[1], oh[2], oh[3]);
}

// ---------------------------------------------------------------------------
// K3: pure GEMM Z = Hn @ W2 + b2 -> per-head LSE -> Z, EXh, SELF2.
// BM=64, BN=128, BK=32, 256 thr (4 waves 2x2, wave 32x64 = one head),
// 24KB dbuf LDS, grid (256,2) = 512 blocks = 2 blocks/CU.
// BOTH operands via global_load_lds (no VALU in staging).
// Chunks/buf: A [0,256), B [256,768)
// ---------------------------------------------------------------------------
__global__ __launch_bounds__(256) void k_gemm2(const u16* __restrict__ Hn,
                                               const u16* __restrict__ W2ht,
                                               const float* __restrict__ b2,
                                               float* __restrict__ Z,
                                               u16* __restrict__ EXh,
                                               float* __restrict__ SELF2) {
  __shared__ u16 sm[2][768 * 8];   // 24 KB
  __shared__ float selfp[64][2];
  const int tid = threadIdx.x;
  const int lane = tid & 63, w = tid >> 6;
  const int wr = w >> 1, wc = w & 1;
  const int gm = blockIdx.x * 64;
  const int n0 = blockIdx.y * 128;

  auto STAGE = [&](int buf, int kt) {
#pragma unroll
    for (int t = 0; t < 3; ++t) {
      const int f = t * 256 + tid;            // [0,768)
      const int isB = (f >= 256);             // wave-uniform (t-granular)
      const int wi = isB ? (f - 256) : f;
      const int grp = wi >> 6, s2 = wi & 63;
      const int row = (isB ? n0 : gm) + grp * 16 + (s2 >> 2);
      const int k16 = (s2 & 3) ^ ((s2 >> 3) & 3);
      const u16* src = isB ? W2ht : Hn;
      gload16(src + ((size_t)row << 11) + (kt << 5) + k16 * 8,
              &sm[buf][(size_t)f * 8]);
    }
  };

  f32x4 acc[2][4];
#pragma unroll
  for (int i = 0; i < 2; ++i)
#pragma unroll
    for (int j = 0; j < 4; ++j) acc[i][j] = (f32x4){0.f, 0.f, 0.f, 0.f};

  const int lr = lane & 15, kc2 = lane >> 4;
  const int rI = lr * 4 + (kc2 ^ ((lr >> 1) & 3));

  STAGE(0, 0);
  for (int kt = 0; kt < 64; ++kt) {
    __syncthreads();
    if (kt + 1 < 64) STAGE((kt + 1) & 1, kt + 1);
    const u16* base = sm[kt & 1];
    short8 ah[2], bh[4];
#pragma unroll
    for (int i = 0; i < 2; ++i)
      ah[i] = *(const short8*)(base + ((wr * 2 + i) * 64 + rI) * 8);
#pragma unroll
    for (int j = 0; j < 4; ++j)
      bh[j] = *(const short8*)(base + (256 + (wc * 4 + j) * 64 + rI) * 8);
#pragma unroll
    for (int i = 0; i < 2; ++i)
#pragma unroll
      for (int j = 0; j < 4; ++j)
        acc[i][j] = __builtin_amdgcn_mfma_f32_16x16x32_bf16(ah[i], bh[j], acc[i][j], 0, 0, 0);
  }

  // fused epilogue: bias + per-head (64-col == this wave's wc) LSE
  const int cc = lane & 15;
  float bias[4];
#pragma unroll
  for (int j = 0; j < 4; ++j) bias[j] = b2[n0 + wc * 64 + j * 16 + cc];

#pragma unroll
  for (int i = 0; i < 2; ++i)
#pragma unroll
    for (int reg = 0; reg < 4; ++reg) {
      const int rl = wr * 32 + i * 16 + ((lane >> 4) << 2) + reg;   // row in [0,64)
      const int row = gm + rl;
      float z[4];
#pragma unroll
      for (int j = 0; j < 4; ++j) z[j] = acc[i][j][reg] + bias[j];
      float mx = fmaxf(fmaxf(z[0], z[1]), fmaxf(z[2], z[3]));
#pragma unroll
      for (int m = 1; m <= 8; m <<= 1) mx = fmaxf(mx, __shfl_xor(mx, m));
      float se = expf(z[0] - mx) + expf(z[1] - mx) + expf(z[2] - mx) + expf(z[3] - mx);
#pragma unroll
      for (int m = 1; m <= 8; m <<= 1) se += __shfl_xor(se, m);
      const float lse = mx + logf(se);
      float selfc = 0.f;
#pragma unroll
      for (int j = 0; j < 4; ++j) {
        const float p = z[j] - lse;
        const float e = expf(p);
        selfc += e * p;
        const size_t o = (size_t)row * DD + n0 + wc * 64 + j * 16 + cc;
        Z[o] = z[j];
        EXh[o] = f2bf(e);
      }
#pragma unroll
      for (int m = 1; m <= 8; m <<= 1) selfc += __shfl_xor(selfc, m);
      if (cc == 0) selfp[rl][wc] = selfc;
    }
  __syncthreads();
  if (tid < 64)
    SELF2[(size_t)(gm + tid) * 2 + blockIdx.y] = selfp[tid][0] + selfp[tid][1];
}

// ---------------------------------------------------------------------------
// K4: LEh = bf16(log(emb)), layout [1024][256]
// ---------------------------------------------------------------------------
__global__ __launch_bounds__(256) void k_prep_le(const float* __restrict__ E,
                                                 u16* __restrict__ LEh) {
  const size_t i = ((size_t)blockIdx.x * 256 + threadIdx.x) * 4;
  float4 v4 = *(const float4*)&E[i];
  const u16 h0 = f2bf(logf(v4.x)), h1 = f2bf(logf(v4.y));
  const u16 h2 = f2bf(logf(v4.z)), h3 = f2bf(logf(v4.w));
  *(uint2*)&LEh[i] = make_uint2((unsigned)h0 | ((unsigned)h1 << 16),
                                (unsigned)h2 | ((unsigned)h3 << 16));
}

// ---------------------------------------------------------------------------
// K5: dots = EX @ LE^T (single bf16 MFMA) with FUSED per-tile argmax.
// 128x128 tile, BK=32, K=256, double-buffered 32KB LDS. PV/PI [N][16].
// XCD-swizzled grid (1024): by=(hw&7)*16+(hw>>6), bx=(hw>>3)&7.
// ---------------------------------------------------------------------------
__global__ __launch_bounds__(256) void k_dots(const u16* __restrict__ EXh,
                                              const u16* __restrict__ LEh,
                                              float* __restrict__ PV, int* __restrict__ PI) {
  __shared__ u16 sm[2][1024 * 8];   // 32 KB
  const int tid = threadIdx.x;
  const int lane = tid & 63, w = tid >> 6;
  const int wr = w >> 1, wc = w & 1;
  const int hw = blockIdx.x;
  const int by = (hw & 7) * 16 + (hw >> 6);   // [0,128)
  const int bx = (hw >> 3) & 7;               // [0,8)
  const int gm = by * 128, m0 = bx * 128;

  f32x4 acc[4][4];
#pragma unroll
  for (int i = 0; i < 4; ++i)
#pragma unroll
    for (int j = 0; j < 4; ++j) acc[i][j] = (f32x4){0.f, 0.f, 0.f, 0.f};

  auto STAGE = [&](int buf, int kt) {
#pragma unroll
    for (int t = 0; t < 4; ++t) {
      const int f = t * 256 + tid;            // [0,1024)
      const int mtx = f >> 9;                 // 0: EX, 1: LE (wave-uniform)
      const int wi = f & 511;
      const int grp = wi >> 6, s2 = wi & 63;
      const int rowbase = mtx ? m0 : gm;
      const int row = rowbase + grp * 16 + (s2 >> 2);
      const int k16 = (s2 & 3) ^ ((s2 >> 3) & 3);
      const u16* src = mtx ? LEh : EXh;
      gload16(src + ((size_t)row << 8) + (kt << 5) + k16 * 8,
              &sm[buf][(size_t)f * 8]);
    }
  };

  STAGE(0, 0);
  const int rI = (lane & 15) * 4 + ((lane >> 4) ^ ((lane >> 1) & 3));
  for (int kt = 0; kt < 8; ++kt) {
    __syncthreads();
    if (kt + 1 < 8) STAGE((kt + 1) & 1, kt + 1);
    const u16* base = sm[kt & 1];
    short8 eh[4], bh[4];
#pragma unroll
    for (int i = 0; i < 4; ++i) {
      eh[i] = *(const short8*)(base + ((wr * 4 + i) * 64 + rI) * 8);
      bh[i] = *(const short8*)(base + (512 + (wc * 4 + i) * 64 + rI) * 8);
    }
#pragma unroll
    for (int i = 0; i < 4; ++i)
#pragma unroll
      for (int j = 0; j < 4; ++j)
        acc[i][j] = __builtin_amdgcn_mfma_f32_16x16x32_bf16(eh[i], bh[j], acc[i][j], 0, 0, 0);
  }

  const int cc = lane & 15;
  const int mtile = bx * 2 + wc;
#pragma unroll
  for (int i = 0; i < 4; ++i)
#pragma unroll
    for (int reg = 0; reg < 4; ++reg) {
      float bv = acc[i][0][reg];
      int bi = m0 + wc * 64 + cc;
#pragma unroll
      for (int j = 1; j < 4; ++j) {
        const float v = acc[i][j][reg];
        if (v > bv) { bv = v; bi = m0 + wc * 64 + j * 16 + cc; }
      }
#pragma unroll
      for (int msk = 8; msk; msk >>= 1) {
        const float ov = __shfl_xor(bv, msk);
        const int   oi = __shfl_xor(bi, msk);
        if (ov > bv || (ov == bv && oi < bi)) { bv = ov; bi = oi; }
      }
      if (cc == 0) {
        const int row = gm + wr * 64 + i * 16 + ((lane >> 4) << 2) + reg;
        PV[row * 16 + mtile] = bv;
        PI[row * 16 + mtile] = bi;
      }
    }
}

// ---------------------------------------------------------------------------
// K6: per row: reduce 16 partials, KL = self - best, gather Q. Wave per row.
// ---------------------------------------------------------------------------
__global__ __launch_bounds__(256) void k_scan(const float* __restrict__ PV,
                                              const int* __restrict__ PI,
                                              const float* __restrict__ SELF2,
                                              const float* __restrict__ E,
                                              float* __restrict__ Q,
                                              float* __restrict__ KL) {
  const int tid = threadIdx.x;
  const int lane = tid & 63;
  const int row = blockIdx.x * 4 + (tid >> 6);

  float bv = -1e30f;
  int bi = 0x7fffffff;
  if (lane < 16) { bv = PV[row * 16 + lane]; bi = PI[row * 16 + lane]; }
#pragma unroll
  for (int m = 32; m; m >>= 1) {
    const float ov = __shfl_xor(bv, m);
    const int   oi = __shfl_xor(bi, m);
    if (ov > bv || (ov == bv && oi < bi)) { bv = ov; bi = oi; }
  }
  if (lane == 0) KL[row] = SELF2[(size_t)row * 2] + SELF2[(size_t)row * 2 + 1] - bv;
  float4 e4 = *(const float4*)&E[((size_t)bi << 8) + lane * 4];
  *(float4*)&Q[((size_t)row << 8) + lane * 4] = e4;
}

// ---------------------------------------------------------------------------
// K7: loss = 0.25/B * sum_n kl[n]*mask[n]
// ---------------------------------------------------------------------------
__global__ __launch_bounds__(256) void k_loss(const float* __restrict__ KL,
                                              const float* __restrict__ MASK,
                                              float* __restrict__ out) {
  __shared__ float red[4];
  const int tid = threadIdx.x;
  float s = 0.f;
  for (int i = tid; i < NROWS; i += 256) s += KL[i] * MASK[i];
#pragma unroll
  for (int m = 32; m; m >>= 1) s += __shfl_xor(s, m);
  if ((tid & 63) == 0) red[tid >> 6] = s;
  __syncthreads();
  if (tid == 0) out[0] = (red[0] + red[1] + red[2] + red[3]) * (0.25f / 16.f);
}

// ---------------------------------------------------------------------------
extern "C" void kernel_launch(void* const* d_in, const int* in_sizes, int n_in,
                              void* d_out, int out_size, void* d_ws, size_t ws_size,
                              hipStream_t stream) {
  const float* x     = (const float*)d_in[0];
  const float* masks = (const float*)d_in[1];
  const float* W1    = (const float*)d_in[2];
  const float* ln_g  = (const float*)d_in[3];
  const float* ln_b  = (const float*)d_in[4];
  const float* W2    = (const float*)d_in[5];
  const float* b2    = (const float*)d_in[6];
  const float* emb   = (const float*)d_in[7];

  float* z_out = (float*)d_out;
  float* q_out = z_out + (size_t)NROWS * DD;
  float* loss_out = z_out + 2 * (size_t)NROWS * DD;

  char* ws = (char*)d_ws;
  u16*   Hh    = (u16*)(ws);                   //  67,108,864 (16384x2048 bf16)
  u16*   W1ht  = (u16*)(ws + 67108864);        //   2,097,152
  u16*   W2ht  = (u16*)(ws + 69206016);        //   1,048,576
  u16*   LEh   = (u16*)(ws + 70254592);        //     524,288
  float* SELF2 = (float*)(ws + 70778880);      //     131,072
  float* KL    = (float*)(ws + 70909952);      //      65,536
  u16*   Xb    = (u16*)(ws + 70975488);        //  16,777,216 -> end 87,752,704
  // overlays:
  float* PV    = (float*)(ws);                 //   1 MB (over Hh; H dead after gemm2)
  int*   PI    = (int*)(ws + 1048576);         //   1 MB
  float* STATS = (float*)q_out;                //   2 MB (q_out; consumed by k_ln before EX written)
  u16*   EXh   = (u16*)q_out;                  //   8 MB (after STATS consumed)

  k_split_x<<<(NROWS * INCH) / 2048, 256, 0, stream>>>(x, Xb);
  k_split_wT<<<dim3(64, 16), 256, 0, stream>>>(W1, W1ht, INCH, CH);
  k_split_wT<<<dim3(8, 64), 256, 0, stream>>>(W2, W2ht, CH, DD);
  k_prep_le<<<256, 256, 0, stream>>>(emb, LEh);

  k_gemm1<<<2048, 256, 0, stream>>>(Xb, W1ht, Hh, STATS);
  k_ln<<<NROWS, 256, 0, stream>>>(Hh, STATS, ln_g, ln_b);
  k_gemm2<<<dim3(NROWS / 64, 2), 256, 0, stream>>>(Hh, W2ht, b2, z_out, EXh, SELF2);

  k_dots<<<1024, 256, 0, stream>>>(EXh, LEh, PV, PI);
  k_scan<<<4096, 256, 0, stream>>>(PV, PI, SELF2, emb, q_out, KL);
  k_loss<<<1, 256, 0, stream>>>(KL, masks, loss_out);
}